// Round 11
// baseline (249.900 us; speedup 1.0000x reference)
//
#include <hip/hip_runtime.h>
#include <math.h>

static constexpr int IMGS = 2;
static constexpr int H = 128, W = 128;
static constexpr int NP = H * W;           // 16384
static constexpr int KWIN = 30;            // quickshift window radius (ceil(3*10))
static constexpr int GR = 20;              // gaussian radius int(4*5+0.5)
static constexpr float INV = 0.005f;       // 0.5 / (10*10)
static constexpr int MAXSEG = 40;

// padded feature layout: row stride 192 float4, cols [30,158) hold the image.
// float4 = (L, a, b, dens); pads = (1e6,1e6,1e6,-inf).
static constexpr int PSTR = 192;
static constexpr int PIMG = H * PSTR;      // 24576 float4 per image

// ---------------- prep: pf sentinel fill + rgb2lab into bufL -------------------
__global__ void k_prep(const float* __restrict__ x, float4* __restrict__ pf,
                       float4* __restrict__ bufL) {
#pragma clang fp contract(off)
  int i = blockIdx.x * blockDim.x + threadIdx.x;
  if (i < IMGS * PIMG) pf[i] = make_float4(1e6f, 1e6f, 1e6f, -__builtin_inff());
  if (i >= IMGS * NP) return;
  int img = i / NP, p = i % NP;
  const float* base = x + img * 3 * NP;
  float rgb[3] = { base[p], base[NP + p], base[2 * NP + p] };
  float lin[3];
  for (int c = 0; c < 3; ++c) {
    float v = rgb[c];
    lin[c] = (v > 0.04045f) ? powf((v + 0.055f) / 1.055f, 2.4f) : (v / 12.92f);
  }
  const float M[3][3] = {{0.412453f, 0.357580f, 0.180423f},
                         {0.212671f, 0.715160f, 0.072169f},
                         {0.019334f, 0.119193f, 0.950227f}};
  const float wp[3] = {0.95047f, 1.0f, 1.08883f};
  float f[3];
  for (int j = 0; j < 3; ++j) {
    float s = lin[0] * M[j][0];
    s = s + lin[1] * M[j][1];
    s = s + lin[2] * M[j][2];
    float xyz = s / wp[j];
    f[j] = (xyz > 0.008856f) ? cbrtf(fmaxf(xyz, 1e-8f))
                             : (7.787f * xyz + (float)(16.0 / 116.0));
  }
  float L = 116.0f * f[1] - 16.0f;
  float a = 500.0f * (f[0] - f[1]);
  float b = 200.0f * (f[1] - f[2]);
  bufL[i] = make_float4(L, a, b, 0.0f);
}

// ---------------- fused separable gaussian (V then H), symmetric pad -----------
__global__ __launch_bounds__(384)
void k_blur(const float4* __restrict__ bufL, float4* __restrict__ pf) {
#pragma clang fp contract(off)
  __shared__ float w[2 * GR + 1];
  __shared__ float mid[3][128];
  if (threadIdx.x == 0) {
    double k[2 * GR + 1];
    double s = 0.0;
    for (int i = -GR; i <= GR; ++i) {
      double t = (double)i / 5.0;
      double v = exp(-0.5 * t * t);
      k[i + GR] = v;
      s += v;
    }
    for (int i = 0; i < 2 * GR + 1; ++i) w[i] = (float)(k[i] / s);
  }
  __syncthreads();
  int tid = threadIdx.x;
  int c = tid >> 7;                         // 0..2
  int xx = tid & 127;
  int b = blockIdx.x;                       // img*128 + y
  int y = b & 127, img = b >> 7;
  const float* base = (const float*)(bufL + img * NP);
  float a = 0.0f;
  for (int t = 0; t <= 2 * GR; ++t) {
    int yy = y - GR + t;
    if (yy < 0) yy = -yy - 1;
    if (yy >= H) yy = 2 * H - 1 - yy;
    a = a + w[t] * base[(yy * W + xx) * 4 + c];
  }
  mid[c][xx] = a;
  __syncthreads();
  float o = 0.0f;
  for (int t = 0; t <= 2 * GR; ++t) {
    int xq = xx - GR + t;
    if (xq < 0) xq = -xq - 1;
    if (xq >= W) xq = 2 * W - 1 - xq;
    o = o + w[t] * mid[c][xq];
  }
  ((float*)(pf + img * PIMG + y * PSTR + xx + KWIN))[c] = o;  // 4B store, no race
}

// ---------------- density: 8-wave producer/folder, exact sequential fold -------
// __expf (native v_exp_f32): ~1e-6 rel dens perturbation, self-consistent; pad
// sentinel still underflows to exact +0.0. Hybrid reads: dcu<31 from staged
// LDS row, dcu>=31 direct global (L1/L2-resident — same bits, same order).
template<int DB, int DE>
__device__ inline void produce_terms(const float4* __restrict__ rb,
                                     const float4* __restrict__ grow,
                                     float* __restrict__ tb,
                                     float4 fc, float sprf, int lane) {
#pragma clang fp contract(off)
#pragma unroll
  for (int dcu = DB; dcu < DE; ++dcu) {
    float4 nb = (dcu < 31) ? rb[lane + dcu] : grow[lane + dcu];
    float d0 = fc.x - nb.x, d1 = fc.y - nb.y, d2 = fc.z - nb.z;
    float d = (d0 * d0 + d1 * d1) + d2 * d2;
    float cdc = (float)((dcu - KWIN) * (dcu - KWIN));
    d = d + (sprf + cdc);                 // exact: both ints < 2^11, sum exact
    tb[dcu * 64 + lane] = __expf(-d * INV); // pad cols -> exact +0.0
  }
}

__global__ __launch_bounds__(512, 4)
void k_dens(float4* __restrict__ pf) {
#pragma clang fp contract(off)
  __shared__ float4 rowbuf[2][128];
  __shared__ float termbuf[2][61][64];
  int tid = threadIdx.x;
  int lane = tid & 63;
  int wave = tid >> 6;
  int b = blockIdx.x;                      // 512 blocks: img*256 + y*2 + tile
  int tile = b & 1, y = (b >> 1) & 127, img = b >> 8;
  int x0 = tile * 64;
  float4* fimg = pf + img * PIMG;
  float4 fc = fimg[y * PSTR + x0 + lane + KWIN];
  int ny0 = y - KWIN; if (ny0 < 0) ny0 = 0;
  int ny1 = y + KWIN; if (ny1 > H - 1) ny1 = H - 1;
  if (wave == 7) {
    const float4* row = fimg + ny0 * PSTR + x0;
    rowbuf[0][lane] = row[lane];
    rowbuf[0][lane + 64] = row[lane + 64];
  }
  __syncthreads();
  float acc = 0.0f;
  for (int ny = ny0; ny <= ny1; ++ny) {    // skipped rows: ref adds exact 0.0
    int kb = (ny - ny0) & 1;
    float4 p0, p1;
    bool pre = (wave == 7) && (ny < ny1);
    if (pre) {                             // issue prefetch early
      const float4* nrow = fimg + (ny + 1) * PSTR + x0;
      p0 = nrow[lane];
      p1 = nrow[lane + 64];
    }
    int dr = ny - y;
    float sprf = (float)(dr * dr);
    const float4* rb = rowbuf[kb];
    const float4* grow = fimg + ny * PSTR + x0;
    float* tb = &termbuf[kb][0][0];
    if      (wave == 1) produce_terms< 0,  9>(rb, grow, tb, fc, sprf, lane);
    else if (wave == 2) produce_terms< 9, 18>(rb, grow, tb, fc, sprf, lane);
    else if (wave == 3) produce_terms<18, 27>(rb, grow, tb, fc, sprf, lane);
    else if (wave == 4) produce_terms<27, 36>(rb, grow, tb, fc, sprf, lane);
    else if (wave == 5) produce_terms<36, 45>(rb, grow, tb, fc, sprf, lane);
    else if (wave == 6) produce_terms<45, 53>(rb, grow, tb, fc, sprf, lane);
    else if (wave == 7) produce_terms<53, 61>(rb, grow, tb, fc, sprf, lane);
    if (pre) {
      rowbuf[kb ^ 1][lane] = p0;
      rowbuf[kb ^ 1][lane + 64] = p1;
    }
    __syncthreads();
    if (wave == 0) {
#pragma unroll
      for (int dcu = 0; dcu < 61; ++dcu)
        acc = acc + termbuf[kb][dcu][lane];     // exact reference order
    }
  }
  if (wave == 0) fimg[y * PSTR + x0 + lane + KWIN].w = acc;
}

// ---------------- parent: half-split 8-wave argmin, pure-global reads ----------
// Grid 1024: (img, y, tile, half). Exactness: candidate index q is strictly
// increasing in the reference's row-major scan order, so min over packed
// (d_bits<<32)|q keys reproduces first-wins tie-break under any partition.
// R10 lesson: the LDS staging + register prefetch caused ~16 B/thread scratch
// (WRITE_SIZE 8.5 MB) and extra VALU. pf is fully L2-resident (1.5 MB) and a
// wave's 61 unrolled loads sweep a ~2 KB L1-resident window — so read
// everything directly from global with immediate offsets. LDS = 4 KB (merge
// buffers only); VGPR pressure minimal; no spill.
__global__ __launch_bounds__(512, 4)
void k_par(const float4* __restrict__ pf, unsigned long long* __restrict__ pkeys) {
#pragma clang fp contract(off)
  __shared__ float m_d[8][64];
  __shared__ int   m_p[8][64];
  int tid = threadIdx.x, lane = tid & 63, wave = tid >> 6;
  int b = blockIdx.x;                      // img*512 + y*4 + tile*2 + half
  int half = b & 1, tile = (b >> 1) & 1, y = (b >> 2) & 127, img = b >> 9;
  int x0 = tile * 64, x = x0 + lane;
  const float4* fimg = pf + img * PIMG;
  float4 fc = fimg[y * PSTR + x + KWIN];
  float dcen = fc.w;
  int ny0 = y - KWIN; if (ny0 < 0) ny0 = 0;
  int ny1 = y + KWIN; if (ny1 > H - 1) ny1 = H - 1;
  int nr = ny1 - ny0 + 1;
  int h0 = nr >> 1;                        // rows in half 0
  int hb = half ? (ny0 + h0) : ny0;
  int he = half ? (ny1 + 1) : (ny0 + h0);
  int nh = he - hb;
  int chunk = (nh + 7) >> 3;
  int rb = hb + wave * chunk;
  int re = rb + chunk; if (re > he) re = he;
  float bestd = __builtin_inff();
  int bestp = y * W + x;
  for (int ny = rb; ny < re; ++ny) {
    int dr = ny - y;
    float sprf = (float)(dr * dr);
    int qbase = ny * W + x;
    const float4* grow = fimg + ny * PSTR + x0 + lane;  // L1/L2-resident
#pragma unroll
    for (int dcu = 0; dcu < 61; ++dcu) {
      float4 nb = grow[dcu];               // immediate offset dcu*16 < 4KB
      float nd = nb.w;                     // pad cols: -inf, never qualifies
      float d0 = fc.x - nb.x, d1 = fc.y - nb.y, d2 = fc.z - nb.z;
      float d = (d0 * d0 + d1 * d1) + d2 * d2;
      float cdc = (float)((dcu - KWIN) * (dcu - KWIN));
      d = d + (sprf + cdc);                // exact (ints < 2^11)
      int better = (nd > dcen) & (d < bestd);
      bestd = better ? d : bestd;
      bestp = better ? (qbase + (dcu - KWIN)) : bestp;
    }
  }
  m_d[wave][lane] = bestd;
  m_p[wave][lane] = bestp;
  __syncthreads();
  if (wave == 0) {
    for (int w = 1; w < 8; ++w) {
      float dw = m_d[w][lane];
      int pw = m_p[w][lane];
      int better = dw < bestd;             // ties keep earlier wave = lower row
      bestd = better ? dw : bestd;
      bestp = better ? pw : bestp;
    }
    // pack (d, q): inf (no candidate) sorts above all finite d
    unsigned long long key =
        ((unsigned long long)__float_as_uint(bestd) << 32) | (unsigned)bestp;
    pkeys[half * (IMGS * NP) + img * NP + y * W + x] = key;
  }
}

// ---------------- merge halves -> parent, zero pres ----------------------------
__global__ void k_merge(const unsigned long long* __restrict__ pkeys,
                        int* __restrict__ parent, int* __restrict__ pres) {
  int i = blockIdx.x * blockDim.x + threadIdx.x;
  if (i >= IMGS * NP) return;
  unsigned long long k0 = pkeys[i], k1 = pkeys[IMGS * NP + i];
  unsigned long long k = (k0 < k1) ? k0 : k1;
  float bd = __uint_as_float((unsigned)(k >> 32));
  int p = i % NP;
  parent[i] = (bd > 400.0f) ? p : (int)(k & 0xffffffffu);  // sqrt(d) > max_dist
  pres[i] = 0;
}

// ---------------- root chase + presence marking --------------------------------
__global__ void k_root(const int* __restrict__ parent, int* __restrict__ root,
                       int* __restrict__ pres) {
  int i = blockIdx.x * blockDim.x + threadIdx.x;
  if (i >= IMGS * NP) return;
  int img = i / NP, p = i % NP;
  const int* par = parent + img * NP;
  int r = par[p];
  for (int it = 0; it < NP; ++it) {        // chains strictly increase density => acyclic
    int pr = par[r];
    if (pr == r) break;
    r = pr;
  }
  root[i] = r;
  pres[img * NP + r] = 1;
}

// ---------------- per-image scan of presence flags + final labels (fused) ------
__global__ void k_scanlabel(const int* __restrict__ root, int* __restrict__ pres,
                            int* __restrict__ out) {
  __shared__ int part[256];
  int img = blockIdx.x;
  int t = threadIdx.x;                     // 256 threads x 64 elements
  int* a = pres + img * NP;
  int base = t * 64;
  int s = 0;
  for (int j = 0; j < 64; ++j) s += a[base + j];
  part[t] = s;
  __syncthreads();
  for (int off = 1; off < 256; off <<= 1) {
    int add = (t >= off) ? part[t - off] : 0;
    __syncthreads();
    part[t] += add;
    __syncthreads();
  }
  int run = part[t] - s;
  for (int j = 0; j < 64; ++j) {
    run += a[base + j];
    a[base + j] = run;
  }
  __syncthreads();
  const int* rimg = root + img * NP;
  int* oimg = out + img * NP;
  for (int j = t; j < NP; j += 256) {
    int lab = a[rimg[j]] - 1;
    oimg[j] = (lab < MAXSEG - 1) ? lab : (MAXSEG - 1);
  }
}

extern "C" void kernel_launch(void* const* d_in, const int* in_sizes, int n_in,
                              void* d_out, int out_size, void* d_ws, size_t ws_size,
                              hipStream_t stream) {
  const float* x = (const float*)d_in[0];
  int* out = (int*)d_out;
  char* ws = (char*)d_ws;

  // workspace layout (~1.75 MB). pkeys aliases bufL — bufL is dead after
  // k_blur, and k_par (which writes pkeys) runs after k_blur in-stream.
  float4* pf   = (float4*)(ws);                         // 2*24576*16 = 786432
  float4* bufL = (float4*)(ws + 786432);                // 524288 (lab output)
  unsigned long long* pkeys = (unsigned long long*)(ws + 786432);  // alias bufL, 524288
  int* parent  = (int*)(ws + 1310720);                  // 131072
  int* root    = (int*)(ws + 1441792);                  // 131072
  int* pres    = (int*)(ws + 1572864);                  // 131072 (zeroed in k_merge)

  const int total = IMGS * NP;                          // 32768
  const int ptotal = IMGS * PIMG;                       // 49152

  k_prep<<<(ptotal + 255) / 256, 256, 0, stream>>>(x, pf, bufL);
  k_blur<<<IMGS * H, 384, 0, stream>>>(bufL, pf);
  k_dens<<<512, 512, 0, stream>>>(pf);
  k_par<<<1024, 512, 0, stream>>>(pf, pkeys);
  k_merge<<<total / 256, 256, 0, stream>>>(pkeys, parent, pres);
  k_root<<<total / 256, 256, 0, stream>>>(parent, root, pres);
  k_scanlabel<<<IMGS, 256, 0, stream>>>(root, pres, out);
}

// Round 12
// 220.811 us; speedup vs baseline: 1.1317x; 1.1317x over previous
//
#include <hip/hip_runtime.h>
#include <math.h>

static constexpr int IMGS = 2;
static constexpr int H = 128, W = 128;
static constexpr int NP = H * W;           // 16384
static constexpr int KWIN = 30;            // quickshift window radius (ceil(3*10))
static constexpr int GR = 20;              // gaussian radius int(4*5+0.5)
static constexpr float INV = 0.005f;       // 0.5 / (10*10)
static constexpr int MAXSEG = 40;

// padded feature layout: row stride 192 float4, cols [30,158) hold the image.
// float4 = (L, a, b, dens); pads = (1e6,1e6,1e6,-inf).
static constexpr int PSTR = 192;
static constexpr int PIMG = H * PSTR;      // 24576 float4 per image

// ---------------- prep: pf sentinel fill + rgb2lab into bufL -------------------
__global__ void k_prep(const float* __restrict__ x, float4* __restrict__ pf,
                       float4* __restrict__ bufL) {
#pragma clang fp contract(off)
  int i = blockIdx.x * blockDim.x + threadIdx.x;
  if (i < IMGS * PIMG) pf[i] = make_float4(1e6f, 1e6f, 1e6f, -__builtin_inff());
  if (i >= IMGS * NP) return;
  int img = i / NP, p = i % NP;
  const float* base = x + img * 3 * NP;
  float rgb[3] = { base[p], base[NP + p], base[2 * NP + p] };
  float lin[3];
  for (int c = 0; c < 3; ++c) {
    float v = rgb[c];
    lin[c] = (v > 0.04045f) ? powf((v + 0.055f) / 1.055f, 2.4f) : (v / 12.92f);
  }
  const float M[3][3] = {{0.412453f, 0.357580f, 0.180423f},
                         {0.212671f, 0.715160f, 0.072169f},
                         {0.019334f, 0.119193f, 0.950227f}};
  const float wp[3] = {0.95047f, 1.0f, 1.08883f};
  float f[3];
  for (int j = 0; j < 3; ++j) {
    float s = lin[0] * M[j][0];
    s = s + lin[1] * M[j][1];
    s = s + lin[2] * M[j][2];
    float xyz = s / wp[j];
    f[j] = (xyz > 0.008856f) ? cbrtf(fmaxf(xyz, 1e-8f))
                             : (7.787f * xyz + (float)(16.0 / 116.0));
  }
  float L = 116.0f * f[1] - 16.0f;
  float a = 500.0f * (f[0] - f[1]);
  float b = 200.0f * (f[1] - f[2]);
  bufL[i] = make_float4(L, a, b, 0.0f);
}

// ---------------- fused separable gaussian (V then H), symmetric pad -----------
__global__ __launch_bounds__(384)
void k_blur(const float4* __restrict__ bufL, float4* __restrict__ pf) {
#pragma clang fp contract(off)
  __shared__ float w[2 * GR + 1];
  __shared__ float mid[3][128];
  if (threadIdx.x == 0) {
    double k[2 * GR + 1];
    double s = 0.0;
    for (int i = -GR; i <= GR; ++i) {
      double t = (double)i / 5.0;
      double v = exp(-0.5 * t * t);
      k[i + GR] = v;
      s += v;
    }
    for (int i = 0; i < 2 * GR + 1; ++i) w[i] = (float)(k[i] / s);
  }
  __syncthreads();
  int tid = threadIdx.x;
  int c = tid >> 7;                         // 0..2
  int xx = tid & 127;
  int b = blockIdx.x;                       // img*128 + y
  int y = b & 127, img = b >> 7;
  const float* base = (const float*)(bufL + img * NP);
  float a = 0.0f;
  for (int t = 0; t <= 2 * GR; ++t) {
    int yy = y - GR + t;
    if (yy < 0) yy = -yy - 1;
    if (yy >= H) yy = 2 * H - 1 - yy;
    a = a + w[t] * base[(yy * W + xx) * 4 + c];
  }
  mid[c][xx] = a;
  __syncthreads();
  float o = 0.0f;
  for (int t = 0; t <= 2 * GR; ++t) {
    int xq = xx - GR + t;
    if (xq < 0) xq = -xq - 1;
    if (xq >= W) xq = 2 * W - 1 - xq;
    o = o + w[t] * mid[c][xq];
  }
  ((float*)(pf + img * PIMG + y * PSTR + xx + KWIN))[c] = o;  // 4B store, no race
}

// ---------------- density: 8-wave producer/folder, exact sequential fold -------
// __expf (native v_exp_f32): ~1e-6 rel dens perturbation, self-consistent; pad
// sentinel still underflows to exact +0.0. Hybrid reads: dcu<31 from staged
// LDS row, dcu>=31 direct global (L1/L2-resident — same bits, same order).
template<int DB, int DE>
__device__ inline void produce_terms(const float4* __restrict__ rb,
                                     const float4* __restrict__ grow,
                                     float* __restrict__ tb,
                                     float4 fc, float sprf, int lane) {
#pragma clang fp contract(off)
#pragma unroll
  for (int dcu = DB; dcu < DE; ++dcu) {
    float4 nb = (dcu < 31) ? rb[lane + dcu] : grow[lane + dcu];
    float d0 = fc.x - nb.x, d1 = fc.y - nb.y, d2 = fc.z - nb.z;
    float d = (d0 * d0 + d1 * d1) + d2 * d2;
    float cdc = (float)((dcu - KWIN) * (dcu - KWIN));
    d = d + (sprf + cdc);                 // exact: both ints < 2^11, sum exact
    tb[dcu * 64 + lane] = __expf(-d * INV); // pad cols -> exact +0.0
  }
}

__global__ __launch_bounds__(512, 4)
void k_dens(float4* __restrict__ pf) {
#pragma clang fp contract(off)
  __shared__ float4 rowbuf[2][128];
  __shared__ float termbuf[2][61][64];
  int tid = threadIdx.x;
  int lane = tid & 63;
  int wave = tid >> 6;
  int b = blockIdx.x;                      // 512 blocks: img*256 + y*2 + tile
  int tile = b & 1, y = (b >> 1) & 127, img = b >> 8;
  int x0 = tile * 64;
  float4* fimg = pf + img * PIMG;
  float4 fc = fimg[y * PSTR + x0 + lane + KWIN];
  int ny0 = y - KWIN; if (ny0 < 0) ny0 = 0;
  int ny1 = y + KWIN; if (ny1 > H - 1) ny1 = H - 1;
  if (wave == 7) {
    const float4* row = fimg + ny0 * PSTR + x0;
    rowbuf[0][lane] = row[lane];
    rowbuf[0][lane + 64] = row[lane + 64];
  }
  __syncthreads();
  float acc = 0.0f;
  for (int ny = ny0; ny <= ny1; ++ny) {    // skipped rows: ref adds exact 0.0
    int kb = (ny - ny0) & 1;
    float4 p0, p1;
    bool pre = (wave == 7) && (ny < ny1);
    if (pre) {                             // issue prefetch early
      const float4* nrow = fimg + (ny + 1) * PSTR + x0;
      p0 = nrow[lane];
      p1 = nrow[lane + 64];
    }
    int dr = ny - y;
    float sprf = (float)(dr * dr);
    const float4* rb = rowbuf[kb];
    const float4* grow = fimg + ny * PSTR + x0;
    float* tb = &termbuf[kb][0][0];
    if      (wave == 1) produce_terms< 0,  9>(rb, grow, tb, fc, sprf, lane);
    else if (wave == 2) produce_terms< 9, 18>(rb, grow, tb, fc, sprf, lane);
    else if (wave == 3) produce_terms<18, 27>(rb, grow, tb, fc, sprf, lane);
    else if (wave == 4) produce_terms<27, 36>(rb, grow, tb, fc, sprf, lane);
    else if (wave == 5) produce_terms<36, 45>(rb, grow, tb, fc, sprf, lane);
    else if (wave == 6) produce_terms<45, 53>(rb, grow, tb, fc, sprf, lane);
    else if (wave == 7) produce_terms<53, 61>(rb, grow, tb, fc, sprf, lane);
    if (pre) {
      rowbuf[kb ^ 1][lane] = p0;
      rowbuf[kb ^ 1][lane + 64] = p1;
    }
    __syncthreads();
    if (wave == 0) {
#pragma unroll
      for (int dcu = 0; dcu < 61; ++dcu)
        acc = acc + termbuf[kb][dcu][lane];     // exact reference order
    }
  }
  if (wave == 0) fimg[y * PSTR + x0 + lane + KWIN].w = acc;
}

// ---------------- parent: half-split 8-wave argmin, chunked hybrid reads -------
// Grid 1024: (img, y, tile, half). Exactness: candidate index q is strictly
// increasing in the reference's row-major scan order, so min over packed
// (d_bits<<32)|q keys reproduces first-wins tie-break under any partition.
// R11 lesson: 61 fully-unrolled global loads -> compiler clusters loads ->
// ~120 MB scratch spill. Fix: per-wave private LDS row staging (no barriers,
// no double-buffer/prefetch) + hybrid reads (dcu<31 LDS / >=31 global, splits
// LDS and vmem pipe pressure) + TEMPLATE CHUNKS of <=8 terms to bound the
// live-load window at 8 float4 = 32 VGPRs.
template<int DB, int DE>
__device__ inline void par_terms(const float4* __restrict__ lrow,
                                 const float4* __restrict__ grow,
                                 float4 fc, float dcen, float sprf, int qbase,
                                 float& bestd, int& bestp) {
#pragma clang fp contract(off)
#pragma unroll
  for (int dcu = DB; dcu < DE; ++dcu) {
    float4 nb = (dcu < 31) ? lrow[dcu] : grow[dcu];
    float nd = nb.w;                       // pad cols: -inf, never qualifies
    float d0 = fc.x - nb.x, d1 = fc.y - nb.y, d2 = fc.z - nb.z;
    float d = (d0 * d0 + d1 * d1) + d2 * d2;
    float cdc = (float)((dcu - KWIN) * (dcu - KWIN));
    d = d + (sprf + cdc);                  // exact (ints < 2^11)
    int better = (nd > dcen) & (d < bestd);
    bestd = better ? d : bestd;
    bestp = better ? (qbase + (dcu - KWIN)) : bestp;
  }
}

__global__ __launch_bounds__(512, 4)
void k_par(const float4* __restrict__ pf, unsigned long long* __restrict__ pkeys) {
#pragma clang fp contract(off)
  __shared__ float4 lrowbuf[8][128];       // per-wave private row stage (16 KB)
  __shared__ float m_d[8][64];
  __shared__ int   m_p[8][64];
  int tid = threadIdx.x, lane = tid & 63, wave = tid >> 6;
  int b = blockIdx.x;                      // img*512 + y*4 + tile*2 + half
  int half = b & 1, tile = (b >> 1) & 1, y = (b >> 2) & 127, img = b >> 9;
  int x0 = tile * 64, x = x0 + lane;
  const float4* fimg = pf + img * PIMG;
  float4 fc = fimg[y * PSTR + x + KWIN];
  float dcen = fc.w;
  int ny0 = y - KWIN; if (ny0 < 0) ny0 = 0;
  int ny1 = y + KWIN; if (ny1 > H - 1) ny1 = H - 1;
  int nr = ny1 - ny0 + 1;
  int h0 = nr >> 1;                        // rows in half 0
  int hb = half ? (ny0 + h0) : ny0;
  int he = half ? (ny1 + 1) : (ny0 + h0);
  int nh = he - hb;
  int chunk = (nh + 7) >> 3;
  int rb = hb + wave * chunk;
  int re = rb + chunk; if (re > he) re = he;
  float bestd = __builtin_inff();
  int bestp = y * W + x;
  for (int ny = rb; ny < re; ++ny) {
    const float4* gr = fimg + ny * PSTR + x0;
    lrowbuf[wave][lane] = gr[lane];        // intra-wave RAW: compiler waits lgkmcnt
    lrowbuf[wave][lane + 64] = gr[lane + 64];
    const float4* lrow = &lrowbuf[wave][lane];
    const float4* grow = gr + lane;
    int dr = ny - y;
    float sprf = (float)(dr * dr);
    int qbase = ny * W + x;
    par_terms< 0,  8>(lrow, grow, fc, dcen, sprf, qbase, bestd, bestp);
    par_terms< 8, 16>(lrow, grow, fc, dcen, sprf, qbase, bestd, bestp);
    par_terms<16, 24>(lrow, grow, fc, dcen, sprf, qbase, bestd, bestp);
    par_terms<24, 31>(lrow, grow, fc, dcen, sprf, qbase, bestd, bestp);
    par_terms<31, 39>(lrow, grow, fc, dcen, sprf, qbase, bestd, bestp);
    par_terms<39, 47>(lrow, grow, fc, dcen, sprf, qbase, bestd, bestp);
    par_terms<47, 54>(lrow, grow, fc, dcen, sprf, qbase, bestd, bestp);
    par_terms<54, 61>(lrow, grow, fc, dcen, sprf, qbase, bestd, bestp);
  }
  m_d[wave][lane] = bestd;
  m_p[wave][lane] = bestp;
  __syncthreads();
  if (wave == 0) {
    for (int w = 1; w < 8; ++w) {
      float dw = m_d[w][lane];
      int pw = m_p[w][lane];
      int better = dw < bestd;             // ties keep earlier wave = lower row
      bestd = better ? dw : bestd;
      bestp = better ? pw : bestp;
    }
    // pack (d, q): inf (no candidate) sorts above all finite d
    unsigned long long key =
        ((unsigned long long)__float_as_uint(bestd) << 32) | (unsigned)bestp;
    pkeys[half * (IMGS * NP) + img * NP + y * W + x] = key;
  }
}

// ---------------- merge halves -> parent, zero pres ----------------------------
__global__ void k_merge(const unsigned long long* __restrict__ pkeys,
                        int* __restrict__ parent, int* __restrict__ pres) {
  int i = blockIdx.x * blockDim.x + threadIdx.x;
  if (i >= IMGS * NP) return;
  unsigned long long k0 = pkeys[i], k1 = pkeys[IMGS * NP + i];
  unsigned long long k = (k0 < k1) ? k0 : k1;
  float bd = __uint_as_float((unsigned)(k >> 32));
  int p = i % NP;
  parent[i] = (bd > 400.0f) ? p : (int)(k & 0xffffffffu);  // sqrt(d) > max_dist
  pres[i] = 0;
}

// ---------------- root chase + presence marking --------------------------------
__global__ void k_root(const int* __restrict__ parent, int* __restrict__ root,
                       int* __restrict__ pres) {
  int i = blockIdx.x * blockDim.x + threadIdx.x;
  if (i >= IMGS * NP) return;
  int img = i / NP, p = i % NP;
  const int* par = parent + img * NP;
  int r = par[p];
  for (int it = 0; it < NP; ++it) {        // chains strictly increase density => acyclic
    int pr = par[r];
    if (pr == r) break;
    r = pr;
  }
  root[i] = r;
  pres[img * NP + r] = 1;
}

// ---------------- per-image scan of presence flags + final labels (fused) ------
__global__ void k_scanlabel(const int* __restrict__ root, int* __restrict__ pres,
                            int* __restrict__ out) {
  __shared__ int part[256];
  int img = blockIdx.x;
  int t = threadIdx.x;                     // 256 threads x 64 elements
  int* a = pres + img * NP;
  int base = t * 64;
  int s = 0;
  for (int j = 0; j < 64; ++j) s += a[base + j];
  part[t] = s;
  __syncthreads();
  for (int off = 1; off < 256; off <<= 1) {
    int add = (t >= off) ? part[t - off] : 0;
    __syncthreads();
    part[t] += add;
    __syncthreads();
  }
  int run = part[t] - s;
  for (int j = 0; j < 64; ++j) {
    run += a[base + j];
    a[base + j] = run;
  }
  __syncthreads();
  const int* rimg = root + img * NP;
  int* oimg = out + img * NP;
  for (int j = t; j < NP; j += 256) {
    int lab = a[rimg[j]] - 1;
    oimg[j] = (lab < MAXSEG - 1) ? lab : (MAXSEG - 1);
  }
}

extern "C" void kernel_launch(void* const* d_in, const int* in_sizes, int n_in,
                              void* d_out, int out_size, void* d_ws, size_t ws_size,
                              hipStream_t stream) {
  const float* x = (const float*)d_in[0];
  int* out = (int*)d_out;
  char* ws = (char*)d_ws;

  // workspace layout (~1.75 MB). pkeys aliases bufL — bufL is dead after
  // k_blur, and k_par (which writes pkeys) runs after k_blur in-stream.
  float4* pf   = (float4*)(ws);                         // 2*24576*16 = 786432
  float4* bufL = (float4*)(ws + 786432);                // 524288 (lab output)
  unsigned long long* pkeys = (unsigned long long*)(ws + 786432);  // alias bufL, 524288
  int* parent  = (int*)(ws + 1310720);                  // 131072
  int* root    = (int*)(ws + 1441792);                  // 131072
  int* pres    = (int*)(ws + 1572864);                  // 131072 (zeroed in k_merge)

  const int total = IMGS * NP;                          // 32768
  const int ptotal = IMGS * PIMG;                       // 49152

  k_prep<<<(ptotal + 255) / 256, 256, 0, stream>>>(x, pf, bufL);
  k_blur<<<IMGS * H, 384, 0, stream>>>(bufL, pf);
  k_dens<<<512, 512, 0, stream>>>(pf);
  k_par<<<1024, 512, 0, stream>>>(pf, pkeys);
  k_merge<<<total / 256, 256, 0, stream>>>(pkeys, parent, pres);
  k_root<<<total / 256, 256, 0, stream>>>(parent, root, pres);
  k_scanlabel<<<IMGS, 256, 0, stream>>>(root, pres, out);
}

// Round 13
// 212.634 us; speedup vs baseline: 1.1753x; 1.0385x over previous
//
#include <hip/hip_runtime.h>
#include <math.h>

static constexpr int IMGS = 2;
static constexpr int H = 128, W = 128;
static constexpr int NP = H * W;           // 16384
static constexpr int KWIN = 30;            // quickshift window radius (ceil(3*10))
static constexpr int GR = 20;              // gaussian radius int(4*5+0.5)
static constexpr float INV = 0.005f;       // 0.5 / (10*10)
static constexpr int MAXSEG = 40;

// padded feature layout: row stride 192 float4, cols [30,158) hold the image.
// float4 = (L, a, b, dens); pads = (1e6,1e6,1e6,-inf).
static constexpr int PSTR = 192;
static constexpr int PIMG = H * PSTR;      // 24576 float4 per image

// ---------------- prep: pf sentinel fill + rgb2lab into bufL -------------------
__global__ void k_prep(const float* __restrict__ x, float4* __restrict__ pf,
                       float4* __restrict__ bufL) {
#pragma clang fp contract(off)
  int i = blockIdx.x * blockDim.x + threadIdx.x;
  if (i < IMGS * PIMG) pf[i] = make_float4(1e6f, 1e6f, 1e6f, -__builtin_inff());
  if (i >= IMGS * NP) return;
  int img = i / NP, p = i % NP;
  const float* base = x + img * 3 * NP;
  float rgb[3] = { base[p], base[NP + p], base[2 * NP + p] };
  float lin[3];
  for (int c = 0; c < 3; ++c) {
    float v = rgb[c];
    lin[c] = (v > 0.04045f) ? powf((v + 0.055f) / 1.055f, 2.4f) : (v / 12.92f);
  }
  const float M[3][3] = {{0.412453f, 0.357580f, 0.180423f},
                         {0.212671f, 0.715160f, 0.072169f},
                         {0.019334f, 0.119193f, 0.950227f}};
  const float wp[3] = {0.95047f, 1.0f, 1.08883f};
  float f[3];
  for (int j = 0; j < 3; ++j) {
    float s = lin[0] * M[j][0];
    s = s + lin[1] * M[j][1];
    s = s + lin[2] * M[j][2];
    float xyz = s / wp[j];
    f[j] = (xyz > 0.008856f) ? cbrtf(fmaxf(xyz, 1e-8f))
                             : (7.787f * xyz + (float)(16.0 / 116.0));
  }
  float L = 116.0f * f[1] - 16.0f;
  float a = 500.0f * (f[0] - f[1]);
  float b = 200.0f * (f[1] - f[2]);
  bufL[i] = make_float4(L, a, b, 0.0f);
}

// ---------------- fused separable gaussian (V then H), symmetric pad -----------
__global__ __launch_bounds__(384)
void k_blur(const float4* __restrict__ bufL, float4* __restrict__ pf) {
#pragma clang fp contract(off)
  __shared__ float w[2 * GR + 1];
  __shared__ float mid[3][128];
  if (threadIdx.x == 0) {
    double k[2 * GR + 1];
    double s = 0.0;
    for (int i = -GR; i <= GR; ++i) {
      double t = (double)i / 5.0;
      double v = exp(-0.5 * t * t);
      k[i + GR] = v;
      s += v;
    }
    for (int i = 0; i < 2 * GR + 1; ++i) w[i] = (float)(k[i] / s);
  }
  __syncthreads();
  int tid = threadIdx.x;
  int c = tid >> 7;                         // 0..2
  int xx = tid & 127;
  int b = blockIdx.x;                       // img*128 + y
  int y = b & 127, img = b >> 7;
  const float* base = (const float*)(bufL + img * NP);
  float a = 0.0f;
  for (int t = 0; t <= 2 * GR; ++t) {
    int yy = y - GR + t;
    if (yy < 0) yy = -yy - 1;
    if (yy >= H) yy = 2 * H - 1 - yy;
    a = a + w[t] * base[(yy * W + xx) * 4 + c];
  }
  mid[c][xx] = a;
  __syncthreads();
  float o = 0.0f;
  for (int t = 0; t <= 2 * GR; ++t) {
    int xq = xx - GR + t;
    if (xq < 0) xq = -xq - 1;
    if (xq >= W) xq = 2 * W - 1 - xq;
    o = o + w[t] * mid[c][xq];
  }
  ((float*)(pf + img * PIMG + y * PSTR + xx + KWIN))[c] = o;  // 4B store, no race
}

// ---------------- density: 8-wave producer/folder, exact sequential fold -------
// __expf (native v_exp_f32): ~1e-6 rel dens perturbation, self-consistent; pad
// sentinel still underflows to exact +0.0. Hybrid reads: dcu<31 from staged
// LDS row, dcu>=31 direct global (L1/L2-resident — same bits, same order).
template<int DB, int DE>
__device__ inline void produce_terms(const float4* __restrict__ rb,
                                     const float4* __restrict__ grow,
                                     float* __restrict__ tb,
                                     float4 fc, float sprf, int lane) {
#pragma clang fp contract(off)
#pragma unroll
  for (int dcu = DB; dcu < DE; ++dcu) {
    float4 nb = (dcu < 31) ? rb[lane + dcu] : grow[lane + dcu];
    float d0 = fc.x - nb.x, d1 = fc.y - nb.y, d2 = fc.z - nb.z;
    float d = (d0 * d0 + d1 * d1) + d2 * d2;
    float cdc = (float)((dcu - KWIN) * (dcu - KWIN));
    d = d + (sprf + cdc);                 // exact: both ints < 2^11, sum exact
    tb[dcu * 64 + lane] = __expf(-d * INV); // pad cols -> exact +0.0
  }
}

__global__ __launch_bounds__(512, 4)
void k_dens(float4* __restrict__ pf) {
#pragma clang fp contract(off)
  __shared__ float4 rowbuf[2][128];
  __shared__ float termbuf[2][61][64];
  int tid = threadIdx.x;
  int lane = tid & 63;
  int wave = tid >> 6;
  int b = blockIdx.x;                      // 512 blocks: img*256 + y*2 + tile
  int tile = b & 1, y = (b >> 1) & 127, img = b >> 8;
  int x0 = tile * 64;
  float4* fimg = pf + img * PIMG;
  float4 fc = fimg[y * PSTR + x0 + lane + KWIN];
  int ny0 = y - KWIN; if (ny0 < 0) ny0 = 0;
  int ny1 = y + KWIN; if (ny1 > H - 1) ny1 = H - 1;
  if (wave == 7) {
    const float4* row = fimg + ny0 * PSTR + x0;
    rowbuf[0][lane] = row[lane];
    rowbuf[0][lane + 64] = row[lane + 64];
  }
  __syncthreads();
  float acc = 0.0f;
  for (int ny = ny0; ny <= ny1; ++ny) {    // skipped rows: ref adds exact 0.0
    int kb = (ny - ny0) & 1;
    float4 p0, p1;
    bool pre = (wave == 7) && (ny < ny1);
    if (pre) {                             // issue prefetch early
      const float4* nrow = fimg + (ny + 1) * PSTR + x0;
      p0 = nrow[lane];
      p1 = nrow[lane + 64];
    }
    int dr = ny - y;
    float sprf = (float)(dr * dr);
    const float4* rb = rowbuf[kb];
    const float4* grow = fimg + ny * PSTR + x0;
    float* tb = &termbuf[kb][0][0];
    if      (wave == 1) produce_terms< 0,  9>(rb, grow, tb, fc, sprf, lane);
    else if (wave == 2) produce_terms< 9, 18>(rb, grow, tb, fc, sprf, lane);
    else if (wave == 3) produce_terms<18, 27>(rb, grow, tb, fc, sprf, lane);
    else if (wave == 4) produce_terms<27, 36>(rb, grow, tb, fc, sprf, lane);
    else if (wave == 5) produce_terms<36, 45>(rb, grow, tb, fc, sprf, lane);
    else if (wave == 6) produce_terms<45, 53>(rb, grow, tb, fc, sprf, lane);
    else if (wave == 7) produce_terms<53, 61>(rb, grow, tb, fc, sprf, lane);
    if (pre) {
      rowbuf[kb ^ 1][lane] = p0;
      rowbuf[kb ^ 1][lane + 64] = p1;
    }
    __syncthreads();
    if (wave == 0) {
#pragma unroll
      for (int dcu = 0; dcu < 61; ++dcu)
        acc = acc + termbuf[kb][dcu][lane];     // exact reference order
    }
  }
  if (wave == 0) fimg[y * PSTR + x0 + lane + KWIN].w = acc;
}

// ---------------- parent: half-split, dc-partitioned 8-wave argmin -------------
// Grid 1024: (img, y, tile, half). Rows split by half across blocks; within a
// block each WAVE owns a dc-chunk (8/8/8/7/8/8/7/7) and loops over the half's
// rows — so a wave issues <=8 global loads per row iteration (the R11/R12
// spill came from 30-61 clustered loads; this bounds it structurally, like
// k_dens' producers). No LDS staging: pf is L2-resident, each wave's stripe is
// contiguous & L1-friendly. Exactness: candidate q = (y+dr)*W+(x+dc) is
// strictly increasing in the reference's row-major scan order, so min over
// packed (d_bits<<32)|q keys reproduces the first-wins tie-break under ANY
// partition (waves x halves included). No fp reassociation.
template<int DB, int DE>
__device__ inline void par_row(const float4* __restrict__ grow,
                               float4 fc, float dcen, float sprf, int qbase,
                               float& bestd, int& bestp) {
#pragma clang fp contract(off)
#pragma unroll
  for (int dcu = DB; dcu < DE; ++dcu) {
    float4 nb = grow[dcu];
    float nd = nb.w;                       // pad cols: -inf, never qualifies
    float d0 = fc.x - nb.x, d1 = fc.y - nb.y, d2 = fc.z - nb.z;
    float d = (d0 * d0 + d1 * d1) + d2 * d2;
    float cdc = (float)((dcu - KWIN) * (dcu - KWIN));
    d = d + (sprf + cdc);                  // exact (ints < 2^11)
    int better = (nd > dcen) & (d < bestd);
    bestd = better ? d : bestd;
    bestp = better ? (qbase + (dcu - KWIN)) : bestp;
  }
}

__global__ __launch_bounds__(512, 4)
void k_par(const float4* __restrict__ pf, unsigned long long* __restrict__ pkeys) {
#pragma clang fp contract(off)
  __shared__ unsigned long long m_k[8][64];
  int tid = threadIdx.x, lane = tid & 63, wave = tid >> 6;
  int b = blockIdx.x;                      // img*512 + y*4 + tile*2 + half
  int half = b & 1, tile = (b >> 1) & 1, y = (b >> 2) & 127, img = b >> 9;
  int x0 = tile * 64, x = x0 + lane;
  const float4* fimg = pf + img * PIMG;
  float4 fc = fimg[y * PSTR + x + KWIN];
  float dcen = fc.w;
  int ny0 = y - KWIN; if (ny0 < 0) ny0 = 0;
  int ny1 = y + KWIN; if (ny1 > H - 1) ny1 = H - 1;
  int nr = ny1 - ny0 + 1;
  int h0 = nr >> 1;                        // rows in half 0
  int hb = half ? (ny0 + h0) : ny0;
  int he = half ? (ny1 + 1) : (ny0 + h0);
  float bestd = __builtin_inff();
  int bestp = y * W + x;
  for (int ny = hb; ny < he; ++ny) {
    int dr = ny - y;
    float sprf = (float)(dr * dr);
    int qbase = ny * W + x;
    const float4* grow = fimg + ny * PSTR + x0 + lane;   // L1/L2-resident
    if      (wave == 0) par_row< 0,  8>(grow, fc, dcen, sprf, qbase, bestd, bestp);
    else if (wave == 1) par_row< 8, 16>(grow, fc, dcen, sprf, qbase, bestd, bestp);
    else if (wave == 2) par_row<16, 24>(grow, fc, dcen, sprf, qbase, bestd, bestp);
    else if (wave == 3) par_row<24, 31>(grow, fc, dcen, sprf, qbase, bestd, bestp);
    else if (wave == 4) par_row<31, 39>(grow, fc, dcen, sprf, qbase, bestd, bestp);
    else if (wave == 5) par_row<39, 47>(grow, fc, dcen, sprf, qbase, bestd, bestp);
    else if (wave == 6) par_row<47, 54>(grow, fc, dcen, sprf, qbase, bestd, bestp);
    else                par_row<54, 61>(grow, fc, dcen, sprf, qbase, bestd, bestp);
  }
  // pack (d, q): inf (no candidate) sorts above all finite d
  m_k[wave][lane] =
      ((unsigned long long)__float_as_uint(bestd) << 32) | (unsigned)bestp;
  __syncthreads();
  if (wave == 0) {
    unsigned long long k = m_k[0][lane];
#pragma unroll
    for (int w = 1; w < 8; ++w) {
      unsigned long long kw = m_k[w][lane];
      k = (kw < k) ? kw : k;
    }
    pkeys[half * (IMGS * NP) + img * NP + y * W + x] = k;
  }
}

// ---------------- merge halves -> parent, zero pres ----------------------------
__global__ void k_merge(const unsigned long long* __restrict__ pkeys,
                        int* __restrict__ parent, int* __restrict__ pres) {
  int i = blockIdx.x * blockDim.x + threadIdx.x;
  if (i >= IMGS * NP) return;
  unsigned long long k0 = pkeys[i], k1 = pkeys[IMGS * NP + i];
  unsigned long long k = (k0 < k1) ? k0 : k1;
  float bd = __uint_as_float((unsigned)(k >> 32));
  int p = i % NP;
  parent[i] = (bd > 400.0f) ? p : (int)(k & 0xffffffffu);  // sqrt(d) > max_dist
  pres[i] = 0;
}

// ---------------- root chase + presence marking --------------------------------
__global__ void k_root(const int* __restrict__ parent, int* __restrict__ root,
                       int* __restrict__ pres) {
  int i = blockIdx.x * blockDim.x + threadIdx.x;
  if (i >= IMGS * NP) return;
  int img = i / NP, p = i % NP;
  const int* par = parent + img * NP;
  int r = par[p];
  for (int it = 0; it < NP; ++it) {        // chains strictly increase density => acyclic
    int pr = par[r];
    if (pr == r) break;
    r = pr;
  }
  root[i] = r;
  pres[img * NP + r] = 1;
}

// ---------------- per-image scan of presence flags + final labels (fused) ------
__global__ void k_scanlabel(const int* __restrict__ root, int* __restrict__ pres,
                            int* __restrict__ out) {
  __shared__ int part[256];
  int img = blockIdx.x;
  int t = threadIdx.x;                     // 256 threads x 64 elements
  int* a = pres + img * NP;
  int base = t * 64;
  int s = 0;
  for (int j = 0; j < 64; ++j) s += a[base + j];
  part[t] = s;
  __syncthreads();
  for (int off = 1; off < 256; off <<= 1) {
    int add = (t >= off) ? part[t - off] : 0;
    __syncthreads();
    part[t] += add;
    __syncthreads();
  }
  int run = part[t] - s;
  for (int j = 0; j < 64; ++j) {
    run += a[base + j];
    a[base + j] = run;
  }
  __syncthreads();
  const int* rimg = root + img * NP;
  int* oimg = out + img * NP;
  for (int j = t; j < NP; j += 256) {
    int lab = a[rimg[j]] - 1;
    oimg[j] = (lab < MAXSEG - 1) ? lab : (MAXSEG - 1);
  }
}

extern "C" void kernel_launch(void* const* d_in, const int* in_sizes, int n_in,
                              void* d_out, int out_size, void* d_ws, size_t ws_size,
                              hipStream_t stream) {
  const float* x = (const float*)d_in[0];
  int* out = (int*)d_out;
  char* ws = (char*)d_ws;

  // workspace layout (~1.75 MB). pkeys aliases bufL — bufL is dead after
  // k_blur, and k_par (which writes pkeys) runs after k_blur in-stream.
  float4* pf   = (float4*)(ws);                         // 2*24576*16 = 786432
  float4* bufL = (float4*)(ws + 786432);                // 524288 (lab output)
  unsigned long long* pkeys = (unsigned long long*)(ws + 786432);  // alias bufL, 524288
  int* parent  = (int*)(ws + 1310720);                  // 131072
  int* root    = (int*)(ws + 1441792);                  // 131072
  int* pres    = (int*)(ws + 1572864);                  // 131072 (zeroed in k_merge)

  const int total = IMGS * NP;                          // 32768
  const int ptotal = IMGS * PIMG;                       // 49152

  k_prep<<<(ptotal + 255) / 256, 256, 0, stream>>>(x, pf, bufL);
  k_blur<<<IMGS * H, 384, 0, stream>>>(bufL, pf);
  k_dens<<<512, 512, 0, stream>>>(pf);
  k_par<<<1024, 512, 0, stream>>>(pf, pkeys);
  k_merge<<<total / 256, 256, 0, stream>>>(pkeys, parent, pres);
  k_root<<<total / 256, 256, 0, stream>>>(parent, root, pres);
  k_scanlabel<<<IMGS, 256, 0, stream>>>(root, pres, out);
}

// Round 14
// 212.493 us; speedup vs baseline: 1.1760x; 1.0007x over previous
//
#include <hip/hip_runtime.h>
#include <math.h>

static constexpr int IMGS = 2;
static constexpr int H = 128, W = 128;
static constexpr int NP = H * W;           // 16384
static constexpr int KWIN = 30;            // quickshift window radius (ceil(3*10))
static constexpr int GR = 20;              // gaussian radius int(4*5+0.5)
static constexpr float INV = 0.005f;       // 0.5 / (10*10)
static constexpr int MAXSEG = 40;

// padded feature layout: row stride 192 float4, cols [30,158) hold the image.
// float4 = (L, a, b, dens); pads = (1e6,1e6,1e6,-inf).
static constexpr int PSTR = 192;
static constexpr int PIMG = H * PSTR;      // 24576 float4 per image

// ---------------- prep: pf sentinel fill + rgb2lab into bufL -------------------
__global__ void k_prep(const float* __restrict__ x, float4* __restrict__ pf,
                       float4* __restrict__ bufL) {
#pragma clang fp contract(off)
  int i = blockIdx.x * blockDim.x + threadIdx.x;
  if (i < IMGS * PIMG) pf[i] = make_float4(1e6f, 1e6f, 1e6f, -__builtin_inff());
  if (i >= IMGS * NP) return;
  int img = i / NP, p = i % NP;
  const float* base = x + img * 3 * NP;
  float rgb[3] = { base[p], base[NP + p], base[2 * NP + p] };
  float lin[3];
  for (int c = 0; c < 3; ++c) {
    float v = rgb[c];
    lin[c] = (v > 0.04045f) ? powf((v + 0.055f) / 1.055f, 2.4f) : (v / 12.92f);
  }
  const float M[3][3] = {{0.412453f, 0.357580f, 0.180423f},
                         {0.212671f, 0.715160f, 0.072169f},
                         {0.019334f, 0.119193f, 0.950227f}};
  const float wp[3] = {0.95047f, 1.0f, 1.08883f};
  float f[3];
  for (int j = 0; j < 3; ++j) {
    float s = lin[0] * M[j][0];
    s = s + lin[1] * M[j][1];
    s = s + lin[2] * M[j][2];
    float xyz = s / wp[j];
    f[j] = (xyz > 0.008856f) ? cbrtf(fmaxf(xyz, 1e-8f))
                             : (7.787f * xyz + (float)(16.0 / 116.0));
  }
  float L = 116.0f * f[1] - 16.0f;
  float a = 500.0f * (f[0] - f[1]);
  float b = 200.0f * (f[1] - f[2]);
  bufL[i] = make_float4(L, a, b, 0.0f);
}

// ---------------- fused separable gaussian (V then H), symmetric pad -----------
__global__ __launch_bounds__(384)
void k_blur(const float4* __restrict__ bufL, float4* __restrict__ pf) {
#pragma clang fp contract(off)
  __shared__ float w[2 * GR + 1];
  __shared__ float mid[3][128];
  if (threadIdx.x == 0) {
    double k[2 * GR + 1];
    double s = 0.0;
    for (int i = -GR; i <= GR; ++i) {
      double t = (double)i / 5.0;
      double v = exp(-0.5 * t * t);
      k[i + GR] = v;
      s += v;
    }
    for (int i = 0; i < 2 * GR + 1; ++i) w[i] = (float)(k[i] / s);
  }
  __syncthreads();
  int tid = threadIdx.x;
  int c = tid >> 7;                         // 0..2
  int xx = tid & 127;
  int b = blockIdx.x;                       // img*128 + y
  int y = b & 127, img = b >> 7;
  const float* base = (const float*)(bufL + img * NP);
  float a = 0.0f;
  for (int t = 0; t <= 2 * GR; ++t) {
    int yy = y - GR + t;
    if (yy < 0) yy = -yy - 1;
    if (yy >= H) yy = 2 * H - 1 - yy;
    a = a + w[t] * base[(yy * W + xx) * 4 + c];
  }
  mid[c][xx] = a;
  __syncthreads();
  float o = 0.0f;
  for (int t = 0; t <= 2 * GR; ++t) {
    int xq = xx - GR + t;
    if (xq < 0) xq = -xq - 1;
    if (xq >= W) xq = 2 * W - 1 - xq;
    o = o + w[t] * mid[c][xq];
  }
  ((float*)(pf + img * PIMG + y * PSTR + xx + KWIN))[c] = o;  // 4B store, no race
}

// ---------------- density: 8-wave producer/folder, exact sequential fold -------
// __expf (native v_exp_f32): ~1e-6 rel dens perturbation, self-consistent; pad
// sentinel still underflows to exact +0.0. Hybrid reads: dcu<31 from staged
// LDS row, dcu>=31 direct global (L1/L2-resident — same bits, same order).
template<int DB, int DE>
__device__ inline void produce_terms(const float4* __restrict__ rb,
                                     const float4* __restrict__ grow,
                                     float* __restrict__ tb,
                                     float4 fc, float sprf, int lane) {
#pragma clang fp contract(off)
#pragma unroll
  for (int dcu = DB; dcu < DE; ++dcu) {
    float4 nb = (dcu < 31) ? rb[lane + dcu] : grow[lane + dcu];
    float d0 = fc.x - nb.x, d1 = fc.y - nb.y, d2 = fc.z - nb.z;
    float d = (d0 * d0 + d1 * d1) + d2 * d2;
    float cdc = (float)((dcu - KWIN) * (dcu - KWIN));
    d = d + (sprf + cdc);                 // exact: both ints < 2^11, sum exact
    tb[dcu * 64 + lane] = __expf(-d * INV); // pad cols -> exact +0.0
  }
}

__global__ __launch_bounds__(512, 4)
void k_dens(float4* __restrict__ pf) {
#pragma clang fp contract(off)
  __shared__ float4 rowbuf[2][128];
  __shared__ float termbuf[2][61][64];
  int tid = threadIdx.x;
  int lane = tid & 63;
  int wave = tid >> 6;
  int b = blockIdx.x;                      // 512 blocks: img*256 + y*2 + tile
  int tile = b & 1, y = (b >> 1) & 127, img = b >> 8;
  int x0 = tile * 64;
  float4* fimg = pf + img * PIMG;
  float4 fc = fimg[y * PSTR + x0 + lane + KWIN];
  int ny0 = y - KWIN; if (ny0 < 0) ny0 = 0;
  int ny1 = y + KWIN; if (ny1 > H - 1) ny1 = H - 1;
  if (wave == 7) {
    const float4* row = fimg + ny0 * PSTR + x0;
    rowbuf[0][lane] = row[lane];
    rowbuf[0][lane + 64] = row[lane + 64];
  }
  __syncthreads();
  float acc = 0.0f;
  for (int ny = ny0; ny <= ny1; ++ny) {    // skipped rows: ref adds exact 0.0
    int kb = (ny - ny0) & 1;
    float4 p0, p1;
    bool pre = (wave == 7) && (ny < ny1);
    if (pre) {                             // issue prefetch early
      const float4* nrow = fimg + (ny + 1) * PSTR + x0;
      p0 = nrow[lane];
      p1 = nrow[lane + 64];
    }
    int dr = ny - y;
    float sprf = (float)(dr * dr);
    const float4* rb = rowbuf[kb];
    const float4* grow = fimg + ny * PSTR + x0;
    float* tb = &termbuf[kb][0][0];
    if      (wave == 1) produce_terms< 0,  9>(rb, grow, tb, fc, sprf, lane);
    else if (wave == 2) produce_terms< 9, 18>(rb, grow, tb, fc, sprf, lane);
    else if (wave == 3) produce_terms<18, 27>(rb, grow, tb, fc, sprf, lane);
    else if (wave == 4) produce_terms<27, 36>(rb, grow, tb, fc, sprf, lane);
    else if (wave == 5) produce_terms<36, 45>(rb, grow, tb, fc, sprf, lane);
    else if (wave == 6) produce_terms<45, 53>(rb, grow, tb, fc, sprf, lane);
    else if (wave == 7) produce_terms<53, 61>(rb, grow, tb, fc, sprf, lane);
    if (pre) {
      rowbuf[kb ^ 1][lane] = p0;
      rowbuf[kb ^ 1][lane + 64] = p1;
    }
    __syncthreads();
    if (wave == 0) {
#pragma unroll
      for (int dcu = 0; dcu < 61; ++dcu)
        acc = acc + termbuf[kb][dcu][lane];     // exact reference order
    }
  }
  if (wave == 0) fimg[y * PSTR + x0 + lane + KWIN].w = acc;
}

// ---------------- parent: half-split, dc-partitioned, hybrid LDS/L1 ------------
// Grid 1024: (img, y, tile, half). All 8 waves iterate the same rows; the row
// is staged ONCE into a shared LDS double-buffer (threads 0-127 store, one
// barrier per row — k_dens-proven). Waves 0-3 (dc 0..31) read the LDS copy,
// waves 4-7 (dc 32..60) read global — splits the ~2 GB of per-term read
// traffic across the LDS (~85 B/cyc/CU) and L1 (~64 B/cyc/CU) pipes; R13 was
// pure-L1 and sat on its ~50 µs bandwidth floor. <=8 loads per wave per row
// keeps the live-load window small (no spill — R11/R12 lesson). Exactness:
// candidate q = (y+dr)*W+(x+dc) is strictly increasing in the reference's
// row-major scan order, so min over packed (d_bits<<32)|q keys reproduces the
// first-wins tie-break under ANY partition. No fp reassociation.
template<int DB, int DE, bool LDS>
__device__ inline void par_row(const float4* __restrict__ lrow,
                               const float4* __restrict__ grow,
                               float4 fc, float dcen, float sprf, int qbase,
                               float& bestd, int& bestp) {
#pragma clang fp contract(off)
#pragma unroll
  for (int dcu = DB; dcu < DE; ++dcu) {
    float4 nb = LDS ? lrow[dcu] : grow[dcu];
    float nd = nb.w;                       // pad cols: -inf, never qualifies
    float d0 = fc.x - nb.x, d1 = fc.y - nb.y, d2 = fc.z - nb.z;
    float d = (d0 * d0 + d1 * d1) + d2 * d2;
    float cdc = (float)((dcu - KWIN) * (dcu - KWIN));
    d = d + (sprf + cdc);                  // exact (ints < 2^11)
    int better = (nd > dcen) & (d < bestd);
    bestd = better ? d : bestd;
    bestp = better ? (qbase + (dcu - KWIN)) : bestp;
  }
}

__global__ __launch_bounds__(512, 4)
void k_par(const float4* __restrict__ pf, unsigned long long* __restrict__ pkeys) {
#pragma clang fp contract(off)
  __shared__ float4 rowbuf[2][128];        // shared row stage (4 KB)
  __shared__ unsigned long long m_k[8][64];
  int tid = threadIdx.x, lane = tid & 63, wave = tid >> 6;
  int b = blockIdx.x;                      // img*512 + y*4 + tile*2 + half
  int half = b & 1, tile = (b >> 1) & 1, y = (b >> 2) & 127, img = b >> 9;
  int x0 = tile * 64, x = x0 + lane;
  const float4* fimg = pf + img * PIMG;
  float4 fc = fimg[y * PSTR + x + KWIN];
  float dcen = fc.w;
  int ny0 = y - KWIN; if (ny0 < 0) ny0 = 0;
  int ny1 = y + KWIN; if (ny1 > H - 1) ny1 = H - 1;
  int nr = ny1 - ny0 + 1;
  int h0 = nr >> 1;                        // rows in half 0
  int hb = half ? (ny0 + h0) : ny0;
  int he = half ? (ny1 + 1) : (ny0 + h0);
  // stage first row (threads 0-127)
  if (tid < 128) rowbuf[0][tid] = fimg[hb * PSTR + x0 + tid];
  __syncthreads();
  float bestd = __builtin_inff();
  int bestp = y * W + x;
  for (int ny = hb; ny < he; ++ny) {
    int kb = (ny - hb) & 1;
    float4 p;
    bool pre = (ny + 1 < he) && (tid < 128);
    if (pre) p = fimg[(ny + 1) * PSTR + x0 + tid];   // prefetch next row
    int dr = ny - y;
    float sprf = (float)(dr * dr);
    int qbase = ny * W + x;
    const float4* lrow = &rowbuf[kb][lane];
    const float4* grow = fimg + ny * PSTR + x0 + lane;   // L1/L2-resident
    if      (wave == 0) par_row< 0,  8, true >(lrow, grow, fc, dcen, sprf, qbase, bestd, bestp);
    else if (wave == 1) par_row< 8, 16, true >(lrow, grow, fc, dcen, sprf, qbase, bestd, bestp);
    else if (wave == 2) par_row<16, 24, true >(lrow, grow, fc, dcen, sprf, qbase, bestd, bestp);
    else if (wave == 3) par_row<24, 32, true >(lrow, grow, fc, dcen, sprf, qbase, bestd, bestp);
    else if (wave == 4) par_row<32, 39, false>(lrow, grow, fc, dcen, sprf, qbase, bestd, bestp);
    else if (wave == 5) par_row<39, 47, false>(lrow, grow, fc, dcen, sprf, qbase, bestd, bestp);
    else if (wave == 6) par_row<47, 54, false>(lrow, grow, fc, dcen, sprf, qbase, bestd, bestp);
    else                par_row<54, 61, false>(lrow, grow, fc, dcen, sprf, qbase, bestd, bestp);
    if (pre) rowbuf[kb ^ 1][tid] = p;      // write other buffer (no race)
    __syncthreads();                       // publish row ny+1 before next iter
  }
  // pack (d, q): inf (no candidate) sorts above all finite d
  m_k[wave][lane] =
      ((unsigned long long)__float_as_uint(bestd) << 32) | (unsigned)bestp;
  __syncthreads();
  if (wave == 0) {
    unsigned long long k = m_k[0][lane];
#pragma unroll
    for (int w = 1; w < 8; ++w) {
      unsigned long long kw = m_k[w][lane];
      k = (kw < k) ? kw : k;
    }
    pkeys[half * (IMGS * NP) + img * NP + y * W + x] = k;
  }
}

// ---------------- merge halves -> parent, zero pres ----------------------------
__global__ void k_merge(const unsigned long long* __restrict__ pkeys,
                        int* __restrict__ parent, int* __restrict__ pres) {
  int i = blockIdx.x * blockDim.x + threadIdx.x;
  if (i >= IMGS * NP) return;
  unsigned long long k0 = pkeys[i], k1 = pkeys[IMGS * NP + i];
  unsigned long long k = (k0 < k1) ? k0 : k1;
  float bd = __uint_as_float((unsigned)(k >> 32));
  int p = i % NP;
  parent[i] = (bd > 400.0f) ? p : (int)(k & 0xffffffffu);  // sqrt(d) > max_dist
  pres[i] = 0;
}

// ---------------- root chase + presence marking --------------------------------
__global__ void k_root(const int* __restrict__ parent, int* __restrict__ root,
                       int* __restrict__ pres) {
  int i = blockIdx.x * blockDim.x + threadIdx.x;
  if (i >= IMGS * NP) return;
  int img = i / NP, p = i % NP;
  const int* par = parent + img * NP;
  int r = par[p];
  for (int it = 0; it < NP; ++it) {        // chains strictly increase density => acyclic
    int pr = par[r];
    if (pr == r) break;
    r = pr;
  }
  root[i] = r;
  pres[img * NP + r] = 1;
}

// ---------------- per-image scan of presence flags + final labels (fused) ------
__global__ void k_scanlabel(const int* __restrict__ root, int* __restrict__ pres,
                            int* __restrict__ out) {
  __shared__ int part[256];
  int img = blockIdx.x;
  int t = threadIdx.x;                     // 256 threads x 64 elements
  int* a = pres + img * NP;
  int base = t * 64;
  int s = 0;
  for (int j = 0; j < 64; ++j) s += a[base + j];
  part[t] = s;
  __syncthreads();
  for (int off = 1; off < 256; off <<= 1) {
    int add = (t >= off) ? part[t - off] : 0;
    __syncthreads();
    part[t] += add;
    __syncthreads();
  }
  int run = part[t] - s;
  for (int j = 0; j < 64; ++j) {
    run += a[base + j];
    a[base + j] = run;
  }
  __syncthreads();
  const int* rimg = root + img * NP;
  int* oimg = out + img * NP;
  for (int j = t; j < NP; j += 256) {
    int lab = a[rimg[j]] - 1;
    oimg[j] = (lab < MAXSEG - 1) ? lab : (MAXSEG - 1);
  }
}

extern "C" void kernel_launch(void* const* d_in, const int* in_sizes, int n_in,
                              void* d_out, int out_size, void* d_ws, size_t ws_size,
                              hipStream_t stream) {
  const float* x = (const float*)d_in[0];
  int* out = (int*)d_out;
  char* ws = (char*)d_ws;

  // workspace layout (~1.75 MB). pkeys aliases bufL — bufL is dead after
  // k_blur, and k_par (which writes pkeys) runs after k_blur in-stream.
  float4* pf   = (float4*)(ws);                         // 2*24576*16 = 786432
  float4* bufL = (float4*)(ws + 786432);                // 524288 (lab output)
  unsigned long long* pkeys = (unsigned long long*)(ws + 786432);  // alias bufL, 524288
  int* parent  = (int*)(ws + 1310720);                  // 131072
  int* root    = (int*)(ws + 1441792);                  // 131072
  int* pres    = (int*)(ws + 1572864);                  // 131072 (zeroed in k_merge)

  const int total = IMGS * NP;                          // 32768
  const int ptotal = IMGS * PIMG;                       // 49152

  k_prep<<<(ptotal + 255) / 256, 256, 0, stream>>>(x, pf, bufL);
  k_blur<<<IMGS * H, 384, 0, stream>>>(bufL, pf);
  k_dens<<<512, 512, 0, stream>>>(pf);
  k_par<<<1024, 512, 0, stream>>>(pf, pkeys);
  k_merge<<<total / 256, 256, 0, stream>>>(pkeys, parent, pres);
  k_root<<<total / 256, 256, 0, stream>>>(parent, root, pres);
  k_scanlabel<<<IMGS, 256, 0, stream>>>(root, pres, out);
}

// Round 15
// 212.468 us; speedup vs baseline: 1.1762x; 1.0001x over previous
//
#include <hip/hip_runtime.h>
#include <math.h>

static constexpr int IMGS = 2;
static constexpr int H = 128, W = 128;
static constexpr int NP = H * W;           // 16384
static constexpr int KWIN = 30;            // quickshift window radius (ceil(3*10))
static constexpr int GR = 20;              // gaussian radius int(4*5+0.5)
static constexpr float INV = 0.005f;       // 0.5 / (10*10)
static constexpr int MAXSEG = 40;

// padded feature layout: row stride 192 float4, cols [30,158) hold the image.
// float4 = (L, a, b, dens); pads = (1e6,1e6,1e6,-inf).
static constexpr int PSTR = 192;
static constexpr int PIMG = H * PSTR;      // 24576 float4 per image

// ---------------- prep: pf sentinel fill + rgb2lab into bufL -------------------
__global__ void k_prep(const float* __restrict__ x, float4* __restrict__ pf,
                       float4* __restrict__ bufL) {
#pragma clang fp contract(off)
  int i = blockIdx.x * blockDim.x + threadIdx.x;
  if (i < IMGS * PIMG) pf[i] = make_float4(1e6f, 1e6f, 1e6f, -__builtin_inff());
  if (i >= IMGS * NP) return;
  int img = i / NP, p = i % NP;
  const float* base = x + img * 3 * NP;
  float rgb[3] = { base[p], base[NP + p], base[2 * NP + p] };
  float lin[3];
  for (int c = 0; c < 3; ++c) {
    float v = rgb[c];
    lin[c] = (v > 0.04045f) ? powf((v + 0.055f) / 1.055f, 2.4f) : (v / 12.92f);
  }
  const float M[3][3] = {{0.412453f, 0.357580f, 0.180423f},
                         {0.212671f, 0.715160f, 0.072169f},
                         {0.019334f, 0.119193f, 0.950227f}};
  const float wp[3] = {0.95047f, 1.0f, 1.08883f};
  float f[3];
  for (int j = 0; j < 3; ++j) {
    float s = lin[0] * M[j][0];
    s = s + lin[1] * M[j][1];
    s = s + lin[2] * M[j][2];
    float xyz = s / wp[j];
    f[j] = (xyz > 0.008856f) ? cbrtf(fmaxf(xyz, 1e-8f))
                             : (7.787f * xyz + (float)(16.0 / 116.0));
  }
  float L = 116.0f * f[1] - 16.0f;
  float a = 500.0f * (f[0] - f[1]);
  float b = 200.0f * (f[1] - f[2]);
  bufL[i] = make_float4(L, a, b, 0.0f);
}

// ---------------- fused separable gaussian (V then H), symmetric pad -----------
__global__ __launch_bounds__(384)
void k_blur(const float4* __restrict__ bufL, float4* __restrict__ pf) {
#pragma clang fp contract(off)
  __shared__ float w[2 * GR + 1];
  __shared__ float mid[3][128];
  if (threadIdx.x == 0) {
    double k[2 * GR + 1];
    double s = 0.0;
    for (int i = -GR; i <= GR; ++i) {
      double t = (double)i / 5.0;
      double v = exp(-0.5 * t * t);
      k[i + GR] = v;
      s += v;
    }
    for (int i = 0; i < 2 * GR + 1; ++i) w[i] = (float)(k[i] / s);
  }
  __syncthreads();
  int tid = threadIdx.x;
  int c = tid >> 7;                         // 0..2
  int xx = tid & 127;
  int b = blockIdx.x;                       // img*128 + y
  int y = b & 127, img = b >> 7;
  const float* base = (const float*)(bufL + img * NP);
  float a = 0.0f;
  for (int t = 0; t <= 2 * GR; ++t) {
    int yy = y - GR + t;
    if (yy < 0) yy = -yy - 1;
    if (yy >= H) yy = 2 * H - 1 - yy;
    a = a + w[t] * base[(yy * W + xx) * 4 + c];
  }
  mid[c][xx] = a;
  __syncthreads();
  float o = 0.0f;
  for (int t = 0; t <= 2 * GR; ++t) {
    int xq = xx - GR + t;
    if (xq < 0) xq = -xq - 1;
    if (xq >= W) xq = 2 * W - 1 - xq;
    o = o + w[t] * mid[c][xq];
  }
  ((float*)(pf + img * PIMG + y * PSTR + xx + KWIN))[c] = o;  // 4B store, no race
}

// ---------------- density: 8-wave producer/folder, exact sequential fold -------
// __expf (native v_exp_f32): ~1e-6 rel dens perturbation, self-consistent; pad
// sentinel still underflows to exact +0.0. Hybrid reads: dcu<31 from staged
// LDS row, dcu>=31 direct global (L1/L2-resident — same bits, same order).
template<int DB, int DE>
__device__ inline void produce_terms(const float4* __restrict__ rb,
                                     const float4* __restrict__ grow,
                                     float* __restrict__ tb,
                                     float4 fc, float sprf, int lane) {
#pragma clang fp contract(off)
#pragma unroll
  for (int dcu = DB; dcu < DE; ++dcu) {
    float4 nb = (dcu < 31) ? rb[lane + dcu] : grow[lane + dcu];
    float d0 = fc.x - nb.x, d1 = fc.y - nb.y, d2 = fc.z - nb.z;
    float d = (d0 * d0 + d1 * d1) + d2 * d2;
    float cdc = (float)((dcu - KWIN) * (dcu - KWIN));
    d = d + (sprf + cdc);                 // exact: both ints < 2^11, sum exact
    tb[dcu * 64 + lane] = __expf(-d * INV); // pad cols -> exact +0.0
  }
}

__global__ __launch_bounds__(512, 4)
void k_dens(float4* __restrict__ pf) {
#pragma clang fp contract(off)
  __shared__ float4 rowbuf[2][128];
  __shared__ float termbuf[2][61][64];
  int tid = threadIdx.x;
  int lane = tid & 63;
  int wave = tid >> 6;
  int b = blockIdx.x;                      // 512 blocks: img*256 + y*2 + tile
  int tile = b & 1, y = (b >> 1) & 127, img = b >> 8;
  int x0 = tile * 64;
  float4* fimg = pf + img * PIMG;
  float4 fc = fimg[y * PSTR + x0 + lane + KWIN];
  int ny0 = y - KWIN; if (ny0 < 0) ny0 = 0;
  int ny1 = y + KWIN; if (ny1 > H - 1) ny1 = H - 1;
  if (wave == 7) {
    const float4* row = fimg + ny0 * PSTR + x0;
    rowbuf[0][lane] = row[lane];
    rowbuf[0][lane + 64] = row[lane + 64];
  }
  __syncthreads();
  float acc = 0.0f;
  for (int ny = ny0; ny <= ny1; ++ny) {    // skipped rows: ref adds exact 0.0
    int kb = (ny - ny0) & 1;
    float4 p0, p1;
    bool pre = (wave == 7) && (ny < ny1);
    if (pre) {                             // issue prefetch early
      const float4* nrow = fimg + (ny + 1) * PSTR + x0;
      p0 = nrow[lane];
      p1 = nrow[lane + 64];
    }
    int dr = ny - y;
    float sprf = (float)(dr * dr);
    const float4* rb = rowbuf[kb];
    const float4* grow = fimg + ny * PSTR + x0;
    float* tb = &termbuf[kb][0][0];
    if      (wave == 1) produce_terms< 0,  9>(rb, grow, tb, fc, sprf, lane);
    else if (wave == 2) produce_terms< 9, 18>(rb, grow, tb, fc, sprf, lane);
    else if (wave == 3) produce_terms<18, 27>(rb, grow, tb, fc, sprf, lane);
    else if (wave == 4) produce_terms<27, 36>(rb, grow, tb, fc, sprf, lane);
    else if (wave == 5) produce_terms<36, 45>(rb, grow, tb, fc, sprf, lane);
    else if (wave == 6) produce_terms<45, 53>(rb, grow, tb, fc, sprf, lane);
    else if (wave == 7) produce_terms<53, 61>(rb, grow, tb, fc, sprf, lane);
    if (pre) {
      rowbuf[kb ^ 1][lane] = p0;
      rowbuf[kb ^ 1][lane + 64] = p1;
    }
    __syncthreads();
    if (wave == 0) {
#pragma unroll
      for (int dcu = 0; dcu < 61; ++dcu)
        acc = acc + termbuf[kb][dcu][lane];     // exact reference order
    }
  }
  if (wave == 0) fimg[y * PSTR + x0 + lane + KWIN].w = acc;
}

// ---------------- parent: half-split, dc-partitioned 8-wave argmin -------------
// (R13 structure — spill-free, ~68 µs; R14 showed read-path variants are
// neutral, so keep the simplest.) Exactness: candidate q = (y+dr)*W+(x+dc) is
// strictly increasing in the reference's row-major scan order, so min over
// packed (d_bits<<32)|q keys reproduces the first-wins tie-break under ANY
// partition. <=8 loads per wave per row bounds the live-load window (no spill).
template<int DB, int DE>
__device__ inline void par_row(const float4* __restrict__ grow,
                               float4 fc, float dcen, float sprf, int qbase,
                               float& bestd, int& bestp) {
#pragma clang fp contract(off)
#pragma unroll
  for (int dcu = DB; dcu < DE; ++dcu) {
    float4 nb = grow[dcu];
    float nd = nb.w;                       // pad cols: -inf, never qualifies
    float d0 = fc.x - nb.x, d1 = fc.y - nb.y, d2 = fc.z - nb.z;
    float d = (d0 * d0 + d1 * d1) + d2 * d2;
    float cdc = (float)((dcu - KWIN) * (dcu - KWIN));
    d = d + (sprf + cdc);                  // exact (ints < 2^11)
    int better = (nd > dcen) & (d < bestd);
    bestd = better ? d : bestd;
    bestp = better ? (qbase + (dcu - KWIN)) : bestp;
  }
}

__global__ __launch_bounds__(512, 4)
void k_par(const float4* __restrict__ pf, unsigned long long* __restrict__ pkeys) {
#pragma clang fp contract(off)
  __shared__ unsigned long long m_k[8][64];
  int tid = threadIdx.x, lane = tid & 63, wave = tid >> 6;
  int b = blockIdx.x;                      // img*512 + y*4 + tile*2 + half
  int half = b & 1, tile = (b >> 1) & 1, y = (b >> 2) & 127, img = b >> 9;
  int x0 = tile * 64, x = x0 + lane;
  const float4* fimg = pf + img * PIMG;
  float4 fc = fimg[y * PSTR + x + KWIN];
  float dcen = fc.w;
  int ny0 = y - KWIN; if (ny0 < 0) ny0 = 0;
  int ny1 = y + KWIN; if (ny1 > H - 1) ny1 = H - 1;
  int nr = ny1 - ny0 + 1;
  int h0 = nr >> 1;                        // rows in half 0
  int hb = half ? (ny0 + h0) : ny0;
  int he = half ? (ny1 + 1) : (ny0 + h0);
  float bestd = __builtin_inff();
  int bestp = y * W + x;
  for (int ny = hb; ny < he; ++ny) {
    int dr = ny - y;
    float sprf = (float)(dr * dr);
    int qbase = ny * W + x;
    const float4* grow = fimg + ny * PSTR + x0 + lane;   // L1/L2-resident
    if      (wave == 0) par_row< 0,  8>(grow, fc, dcen, sprf, qbase, bestd, bestp);
    else if (wave == 1) par_row< 8, 16>(grow, fc, dcen, sprf, qbase, bestd, bestp);
    else if (wave == 2) par_row<16, 24>(grow, fc, dcen, sprf, qbase, bestd, bestp);
    else if (wave == 3) par_row<24, 31>(grow, fc, dcen, sprf, qbase, bestd, bestp);
    else if (wave == 4) par_row<31, 39>(grow, fc, dcen, sprf, qbase, bestd, bestp);
    else if (wave == 5) par_row<39, 47>(grow, fc, dcen, sprf, qbase, bestd, bestp);
    else if (wave == 6) par_row<47, 54>(grow, fc, dcen, sprf, qbase, bestd, bestp);
    else                par_row<54, 61>(grow, fc, dcen, sprf, qbase, bestd, bestp);
  }
  // pack (d, q): inf (no candidate) sorts above all finite d
  m_k[wave][lane] =
      ((unsigned long long)__float_as_uint(bestd) << 32) | (unsigned)bestp;
  __syncthreads();
  if (wave == 0) {
    unsigned long long k = m_k[0][lane];
#pragma unroll
    for (int w = 1; w < 8; ++w) {
      unsigned long long kw = m_k[w][lane];
      k = (kw < k) ? kw : k;
    }
    pkeys[half * (IMGS * NP) + img * NP + y * W + x] = k;
  }
}

// ---------------- merge halves -> parent, init root=-1 -------------------------
__global__ void k_merge(const unsigned long long* __restrict__ pkeys,
                        int* __restrict__ parent, int* __restrict__ root) {
  int i = blockIdx.x * blockDim.x + threadIdx.x;
  if (i >= IMGS * NP) return;
  unsigned long long k0 = pkeys[i], k1 = pkeys[IMGS * NP + i];
  unsigned long long k = (k0 < k1) ? k0 : k1;
  float bd = __uint_as_float((unsigned)(k >> 32));
  int p = i % NP;
  parent[i] = (bd > 400.0f) ? p : (int)(k & 0xffffffffu);  // sqrt(d) > max_dist
  root[i] = -1;                            // enables the k_root shortcut
}

// ---------------- root chase with published-root shortcut ----------------------
// root[j] only ever transitions -1 -> final root of j (single aligned 4B
// write), so a racy read returns -1 (no shortcut — safe) or the correct root.
// XCD L2 non-coherence can only make the shortcut less effective, never wrong.
// Both loads per step (root[r], par[r]) are independent — issued in parallel,
// so the shortcut adds no latency to the chase.
__global__ void k_root(const int* __restrict__ parent, int* __restrict__ root) {
  int i = blockIdx.x * blockDim.x + threadIdx.x;
  if (i >= IMGS * NP) return;
  int img = i / NP, p = i % NP;
  const int* par = parent + img * NP;
  volatile int* rt = (volatile int*)(root + img * NP);
  int r = par[p];
#pragma unroll 1
  for (int it = 0; it < NP; ++it) {        // chains strictly increase density => acyclic
    int rr = rt[r];                        // published root of r (or -1)
    int pr = par[r];
    if (rr >= 0) { r = rr; break; }
    if (pr == r) break;
    r = pr;
  }
  root[i] = r;
}

// ---------------- scan of root flags + final labels (fused, coalesced) ---------
// Root flags derived directly from parent: pres[i] in the reference equals
// (parent[i]==i) — flattened-parent values are exactly the fixed points of
// parent (every chain ends at a fixed point; every fixed point maps to
// itself). 1024 threads, int4 coalesced loads, register prefix + LDS scan.
__global__ __launch_bounds__(1024)
void k_scanlabel(const int* __restrict__ parent, const int* __restrict__ root,
                 int* __restrict__ cums, int* __restrict__ out) {
  __shared__ int part[1024];
  int img = blockIdx.x;
  int t = threadIdx.x;                     // 1024 threads x 16 elements
  const int* par = parent + img * NP;
  int base = t * 16;
  int f[16];
  const int4* p4 = (const int4*)(par + base);
#pragma unroll
  for (int j = 0; j < 4; ++j) {
    int4 v = p4[j];
    f[4 * j + 0] = (v.x == base + 4 * j + 0);
    f[4 * j + 1] = (v.y == base + 4 * j + 1);
    f[4 * j + 2] = (v.z == base + 4 * j + 2);
    f[4 * j + 3] = (v.w == base + 4 * j + 3);
  }
  int s = 0;
#pragma unroll
  for (int j = 0; j < 16; ++j) s += f[j];
  part[t] = s;
  __syncthreads();
  for (int off = 1; off < 1024; off <<= 1) {
    int add = (t >= off) ? part[t - off] : 0;
    __syncthreads();
    part[t] += add;
    __syncthreads();
  }
  int run = part[t] - s;                   // exclusive prefix of this chunk
  int* c = cums + img * NP;
#pragma unroll
  for (int j = 0; j < 16; ++j) { run += f[j]; c[base + j] = run; }
  __threadfence_block();
  __syncthreads();                         // block-visible global writes
  const int* rimg = root + img * NP;
  int* oimg = out + img * NP;
  for (int j = t; j < NP; j += 1024) {
    int lab = c[rimg[j]] - 1;
    oimg[j] = (lab < MAXSEG - 1) ? lab : (MAXSEG - 1);
  }
}

extern "C" void kernel_launch(void* const* d_in, const int* in_sizes, int n_in,
                              void* d_out, int out_size, void* d_ws, size_t ws_size,
                              hipStream_t stream) {
  const float* x = (const float*)d_in[0];
  int* out = (int*)d_out;
  char* ws = (char*)d_ws;

  // workspace layout (~1.75 MB). pkeys aliases bufL — bufL is dead after
  // k_blur, and k_par (which writes pkeys) runs after k_blur in-stream.
  float4* pf   = (float4*)(ws);                         // 2*24576*16 = 786432
  float4* bufL = (float4*)(ws + 786432);                // 524288 (lab output)
  unsigned long long* pkeys = (unsigned long long*)(ws + 786432);  // alias bufL, 524288
  int* parent  = (int*)(ws + 1310720);                  // 131072
  int* root    = (int*)(ws + 1441792);                  // 131072
  int* cums    = (int*)(ws + 1572864);                  // 131072

  const int total = IMGS * NP;                          // 32768
  const int ptotal = IMGS * PIMG;                       // 49152

  k_prep<<<(ptotal + 255) / 256, 256, 0, stream>>>(x, pf, bufL);
  k_blur<<<IMGS * H, 384, 0, stream>>>(bufL, pf);
  k_dens<<<512, 512, 0, stream>>>(pf);
  k_par<<<1024, 512, 0, stream>>>(pf, pkeys);
  k_merge<<<total / 256, 256, 0, stream>>>(pkeys, parent, root);
  k_root<<<total / 256, 256, 0, stream>>>(parent, root);
  k_scanlabel<<<IMGS, 1024, 0, stream>>>(parent, root, cums, out);
}